// Round 2
// baseline (1163.251 us; speedup 1.0000x reference)
//
#include <hip/hip_runtime.h>
#include <math.h>

#define N_ROWS 8192
#define A_ART  32
#define D_DIM  768
#define O_DIM  256
#define LN_EPS 1e-5f
#define R_TILE 16
#define P_STR  772   // pooled LDS leading dim: bank = (4r+d)%32 -> <=2-way (free)

typedef unsigned short u16;
typedef unsigned int   u32;

__device__ __forceinline__ float bf2f(u16 u) { return __uint_as_float(((u32)u) << 16); }
__device__ __forceinline__ u16 f2bf(float f) {
    u32 x = __float_as_uint(f);
    return (u16)((x + 0x7fffu + ((x >> 16) & 1u)) >> 16);  // RNE
}
__device__ __forceinline__ float cvt(float v) { return v; }
__device__ __forceinline__ float cvt(u16 v)   { return bf2f(v); }

// ws layout (bytes):
//   0       int flags[2]           {articles_is_bf16, counts_is_int64}
//   256     projw_f32  [768*256]   786432 B
//   786688  params_f32 [1824]      attn_w[0:768] attn_b[768] proj_b[800:1056]
//                                  ln_w[1056:1312] ln_b[1312:1568] no_news[1568:1824]
//   793984  pooled     [8192*768]  25165824 B
#define WS_PROJW   256
#define WS_PARAMS  786688
#define WS_POOLED  793984
#define P_ATTNB    768
#define P_PROJB    800
#define P_LNW      1056
#define P_LNB      1312
#define P_NONEWS   1568

// ---------------- dtype detection ----------------
__global__ __launch_bounds__(64) void detect_kernel(const u32* __restrict__ art_w,
                                                    const int* __restrict__ cnt_w,
                                                    int* __restrict__ flags) {
    const int lane = threadIdx.x;
    // articles: if truly bf16, low 16 bits of each word are a sane bf16 value
    u32 w = art_w[lane];
    u32 low = w & 0xffffu;
    u32 e = (low >> 7) & 0xffu;
    bool sane = (e >= 100u && e <= 140u) || ((low & 0x7fffu) == 0u);
    unsigned long long m1 = __ballot(sane);
    // counts: if int64 (little-endian, values < 2^31), all odd words are 0
    bool hz = true;
    if (lane < 32) hz = (cnt_w[2 * lane + 1] == 0);
    unsigned long long m2 = __ballot(hz);
    if (lane == 0) {
        flags[0] = (__popcll(m1) >= 48) ? 1 : 0;
        flags[1] = (m2 == ~0ull) ? 1 : 0;
    }
}

__device__ __forceinline__ float ldf(const void* p, int i, bool bf) {
    return bf ? bf2f(((const u16*)p)[i]) : ((const float*)p)[i];
}

// ---------------- convert all params to f32 in ws ----------------
__global__ __launch_bounds__(256) void params_kernel(const void* attn_w, const void* attn_b,
                                                     const void* proj_b, const void* ln_w,
                                                     const void* ln_b, const void* no_news,
                                                     const void* proj_w,
                                                     const int* __restrict__ flags,
                                                     float* __restrict__ projw_f,
                                                     float* __restrict__ params_f) {
    const bool bf = flags[0] != 0;
    const int b = blockIdx.x, t = threadIdx.x;
    if (b < 768) {
        int i = b * 256 + t;                       // proj_w element
        projw_f[i] = ldf(proj_w, i, bf);
    } else {
        int i = (b - 768) * 256 + t;               // param slot
        if (i < 768)                    params_f[i] = ldf(attn_w, i, bf);
        else if (i == P_ATTNB)          params_f[i] = ldf(attn_b, 0, bf);
        else if (i >= P_PROJB  && i < P_PROJB  + 256) params_f[i] = ldf(proj_b,  i - P_PROJB,  bf);
        else if (i >= P_LNW    && i < P_LNW    + 256) params_f[i] = ldf(ln_w,    i - P_LNW,    bf);
        else if (i >= P_LNB    && i < P_LNB    + 256) params_f[i] = ldf(ln_b,    i - P_LNB,    bf);
        else if (i >= P_NONEWS && i < P_NONEWS + 256) params_f[i] = ldf(no_news, i - P_NONEWS, bf);
    }
}

// ---------------- masked attention pool (templated on articles dtype) ----------------
template <typename T>
__global__ __launch_bounds__(256) void pool_kernel(const T* __restrict__ articles,
                                                   const int* __restrict__ counts32,
                                                   const int* __restrict__ flags,
                                                   const float* __restrict__ params_f,
                                                   float* __restrict__ pooled) {
    const bool want_bf = (sizeof(T) == 2);
    if ((flags[0] != 0) != want_bf) return;        // dead variant exits
    const int n = blockIdx.x, t = threadIdx.x;
    const int c = counts32[flags[1] ? 2 * n : n];

    if (c <= 0) {
        #pragma unroll
        for (int j = 0; j < 3; ++j) pooled[(size_t)n * D_DIM + t + 256 * j] = 0.0f;
        return;
    }

    __shared__ float lds_scores[A_ART];
    __shared__ float lds_w[A_ART];

    const int wave = t >> 6, lane = t & 63;
    const T* rowbase = articles + (size_t)n * A_ART * D_DIM;

    // scores: one article per wave per iter, x2-vectorized coalesced loads
    for (int a = wave; a < c; a += 4) {
        float s = 0.f;
        if (sizeof(T) == 2) {
            const u32* ap = (const u32*)(rowbase + a * D_DIM);
            #pragma unroll
            for (int j = 0; j < 6; ++j) {
                u32 w = ap[lane + 64 * j];
                int d = 2 * (lane + 64 * j);
                s += bf2f((u16)(w & 0xffffu)) * params_f[d]
                   + bf2f((u16)(w >> 16))     * params_f[d + 1];
            }
        } else {
            const float2* ap = (const float2*)(rowbase + a * D_DIM);
            #pragma unroll
            for (int j = 0; j < 6; ++j) {
                float2 w = ap[lane + 64 * j];
                int d = 2 * (lane + 64 * j);
                s += w.x * params_f[d] + w.y * params_f[d + 1];
            }
        }
        #pragma unroll
        for (int off = 32; off; off >>= 1) s += __shfl_xor(s, off);
        if (lane == 0) lds_scores[a] = s + params_f[P_ATTNB];
    }
    __syncthreads();

    // masked softmax over a < c (ref's -1e9 entries underflow to exactly 0)
    float m = -1e30f;
    for (int a = 0; a < c; ++a) m = fmaxf(m, lds_scores[a]);
    float ssum = 0.f;
    for (int a = 0; a < c; ++a) ssum += __expf(lds_scores[a] - m);
    if (t < c) lds_w[t] = __expf(lds_scores[t] - m) / ssum;
    __syncthreads();

    // pooled[d] = sum_a w[a]*art[a][d]; re-reads hit L2 (row <= 96 KB)
    #pragma unroll
    for (int j = 0; j < 3; ++j) {
        const int d = t + 256 * j;
        float acc = 0.f;
        for (int a = 0; a < c; ++a)
            acc = fmaf(lds_w[a], cvt(rowbase[a * D_DIM + d]), acc);
        pooled[(size_t)n * D_DIM + d] = acc;
    }
}

// ---------------- projection + LN + GELU + no_news select ----------------
__global__ __launch_bounds__(256) void proj_kernel(const float* __restrict__ pooled,
                                                   const float* __restrict__ projw_f,
                                                   const float* __restrict__ params_f,
                                                   const int* __restrict__ counts32,
                                                   const int* __restrict__ flags,
                                                   void* __restrict__ out) {
    __shared__ float lds_p[R_TILE * P_STR];
    __shared__ float lds_s[R_TILE * 16];
    __shared__ float lds_q[R_TILE * 16];
    __shared__ float lds_mu[R_TILE];
    __shared__ float lds_rs[R_TILE];

    const int t = threadIdx.x;
    const int row0 = blockIdx.x * R_TILE;
    const bool out_bf = flags[0] != 0;
    const bool c64 = flags[1] != 0;

    const float4* src = (const float4*)(pooled + (size_t)row0 * D_DIM);
    for (int q = t; q < R_TILE * (D_DIM / 4); q += 256) {
        int r  = q / (D_DIM / 4);
        int dc = (q % (D_DIM / 4)) * 4;
        *((float4*)&lds_p[r * P_STR + dc]) = src[q];
    }
    __syncthreads();

    const int r  = t & 15;
    const int ob = (t >> 4) * 16;

    float acc[16];
    #pragma unroll
    for (int j = 0; j < 16; ++j) acc[j] = 0.f;

    for (int d = 0; d < D_DIM; ++d) {
        const float pv = lds_p[r * P_STR + d];
        const float4* wrow = (const float4*)(projw_f + d * O_DIM + ob);
        float4 wa = wrow[0], wb = wrow[1], wc = wrow[2], wd = wrow[3];
        acc[0]  = fmaf(pv, wa.x, acc[0]);  acc[1]  = fmaf(pv, wa.y, acc[1]);
        acc[2]  = fmaf(pv, wa.z, acc[2]);  acc[3]  = fmaf(pv, wa.w, acc[3]);
        acc[4]  = fmaf(pv, wb.x, acc[4]);  acc[5]  = fmaf(pv, wb.y, acc[5]);
        acc[6]  = fmaf(pv, wb.z, acc[6]);  acc[7]  = fmaf(pv, wb.w, acc[7]);
        acc[8]  = fmaf(pv, wc.x, acc[8]);  acc[9]  = fmaf(pv, wc.y, acc[9]);
        acc[10] = fmaf(pv, wc.z, acc[10]); acc[11] = fmaf(pv, wc.w, acc[11]);
        acc[12] = fmaf(pv, wd.x, acc[12]); acc[13] = fmaf(pv, wd.y, acc[13]);
        acc[14] = fmaf(pv, wd.z, acc[14]); acc[15] = fmaf(pv, wd.w, acc[15]);
    }

    float ps = 0.f, pq = 0.f;
    #pragma unroll
    for (int j = 0; j < 16; ++j) {
        acc[j] += params_f[P_PROJB + ob + j];
        ps += acc[j];
        pq += acc[j] * acc[j];
    }
    lds_s[r * 16 + (t >> 4)] = ps;
    lds_q[r * 16 + (t >> 4)] = pq;
    __syncthreads();

    if (t < 16) {
        float s = 0.f, q = 0.f;
        #pragma unroll
        for (int g = 0; g < 16; ++g) { s += lds_s[t * 16 + g]; q += lds_q[t * 16 + g]; }
        float mu  = s * (1.0f / O_DIM);
        float var = q * (1.0f / O_DIM) - mu * mu;
        lds_mu[t] = mu;
        lds_rs[t] = rsqrtf(var + LN_EPS);
    }
    __syncthreads();

    const float mu = lds_mu[r];
    const float rs = lds_rs[r];
    const int row = row0 + r;
    const int cnt = counts32[c64 ? 2 * row : row];

    float vals[16];
    #pragma unroll
    for (int j = 0; j < 16; ++j) {
        const int o = ob + j;
        float x = (acc[j] - mu) * rs * params_f[P_LNW + o] + params_f[P_LNB + o];
        float g = 0.5f * x * (1.0f + erff(x * 0.70710678118654752f));
        vals[j] = (cnt > 0) ? g : params_f[P_NONEWS + o];
    }

    if (out_bf) {
        u16 obuf[16];
        #pragma unroll
        for (int j = 0; j < 16; ++j) obuf[j] = f2bf(vals[j]);
        uint4* dst = (uint4*)((u16*)out + (size_t)row * O_DIM + ob);
        dst[0] = *((const uint4*)&obuf[0]);
        dst[1] = *((const uint4*)&obuf[8]);
    } else {
        float4* dst = (float4*)((float*)out + (size_t)row * O_DIM + ob);
        dst[0] = *((const float4*)&vals[0]);
        dst[1] = *((const float4*)&vals[4]);
        dst[2] = *((const float4*)&vals[8]);
        dst[3] = *((const float4*)&vals[12]);
    }
}

extern "C" void kernel_launch(void* const* d_in, const int* in_sizes, int n_in,
                              void* d_out, int out_size, void* d_ws, size_t ws_size,
                              hipStream_t stream) {
    const void* articles = d_in[0];
    const int*  counts   = (const int*)d_in[1];
    const void* attn_w   = d_in[2];
    const void* attn_b   = d_in[3];
    const void* proj_w   = d_in[4];
    const void* proj_b   = d_in[5];
    const void* ln_w     = d_in[6];
    const void* ln_b     = d_in[7];
    const void* no_news  = d_in[8];

    int*   flags    = (int*)d_ws;
    float* projw_f  = (float*)((char*)d_ws + WS_PROJW);
    float* params_f = (float*)((char*)d_ws + WS_PARAMS);
    float* pooled   = (float*)((char*)d_ws + WS_POOLED);

    detect_kernel<<<1, 64, 0, stream>>>((const u32*)articles, counts, flags);
    params_kernel<<<776, 256, 0, stream>>>(attn_w, attn_b, proj_b, ln_w, ln_b, no_news,
                                           proj_w, flags, projw_f, params_f);
    pool_kernel<u16><<<N_ROWS, 256, 0, stream>>>((const u16*)articles, counts, flags,
                                                 params_f, pooled);
    pool_kernel<float><<<N_ROWS, 256, 0, stream>>>((const float*)articles, counts, flags,
                                                   params_f, pooled);
    proj_kernel<<<N_ROWS / R_TILE, 256, 0, stream>>>(pooled, projw_f, params_f, counts,
                                                     flags, d_out);
}

// Round 3
// 1141.312 us; speedup vs baseline: 1.0192x; 1.0192x over previous
//
#include <hip/hip_runtime.h>
#include <math.h>

#define N_ROWS 8192
#define A_ART  32
#define D_DIM  768
#define O_DIM  256
#define LN_EPS 1e-5f
#define R_TILE 16
#define P_STR  772   // pooled LDS leading dim: bank = (4r+d)%32 -> <=2-way (free)

typedef unsigned short u16;
typedef unsigned int   u32;

__device__ __forceinline__ float bf2f(u16 u) { return __uint_as_float(((u32)u) << 16); }
__device__ __forceinline__ u16 f2bf(float f) {
    u32 x = __float_as_uint(f);
    return (u16)((x + 0x7fffu + ((x >> 16) & 1u)) >> 16);  // RNE
}

// ws layout (bytes):
//   0       int flags[2]           {articles_is_bf16, counts_is_int64}
//   256     projw_f32  [768*256]   786432 B
//   786688  params_f32 [1824]
//   793984  pooled     [8192*768]  25165824 B
#define WS_PROJW   256
#define WS_PARAMS  786688
#define WS_POOLED  793984
#define P_ATTNB    768
#define P_PROJB    800
#define P_LNW      1056
#define P_LNB      1312
#define P_NONEWS   1568

// ---------------- dtype detection ----------------
__global__ __launch_bounds__(64) void detect_kernel(const u32* __restrict__ art_w,
                                                    const int* __restrict__ cnt_w,
                                                    int* __restrict__ flags) {
    const int lane = threadIdx.x;
    u32 w = art_w[lane];
    u32 low = w & 0xffffu;
    u32 e = (low >> 7) & 0xffu;
    bool sane = (e >= 100u && e <= 140u) || ((low & 0x7fffu) == 0u);
    unsigned long long m1 = __ballot(sane);
    bool hz = true;
    if (lane < 32) hz = (cnt_w[2 * lane + 1] == 0);
    unsigned long long m2 = __ballot(hz);
    if (lane == 0) {
        flags[0] = (__popcll(m1) >= 48) ? 1 : 0;
        flags[1] = (m2 == ~0ull) ? 1 : 0;
    }
}

__device__ __forceinline__ float ldf(const void* p, int i, bool bf) {
    return bf ? bf2f(((const u16*)p)[i]) : ((const float*)p)[i];
}

// ---------------- convert all params to f32 in ws ----------------
__global__ __launch_bounds__(256) void params_kernel(const void* attn_w, const void* attn_b,
                                                     const void* proj_b, const void* ln_w,
                                                     const void* ln_b, const void* no_news,
                                                     const void* proj_w,
                                                     const int* __restrict__ flags,
                                                     float* __restrict__ projw_f,
                                                     float* __restrict__ params_f) {
    const bool bf = flags[0] != 0;
    const int b = blockIdx.x, t = threadIdx.x;
    if (b < 768) {
        int i = b * 256 + t;
        projw_f[i] = ldf(proj_w, i, bf);
    } else {
        int i = (b - 768) * 256 + t;
        if (i < 768)                    params_f[i] = ldf(attn_w, i, bf);
        else if (i == P_ATTNB)          params_f[i] = ldf(attn_b, 0, bf);
        else if (i >= P_PROJB  && i < P_PROJB  + 256) params_f[i] = ldf(proj_b,  i - P_PROJB,  bf);
        else if (i >= P_LNW    && i < P_LNW    + 256) params_f[i] = ldf(ln_w,    i - P_LNW,    bf);
        else if (i >= P_LNB    && i < P_LNB    + 256) params_f[i] = ldf(ln_b,    i - P_LNB,    bf);
        else if (i >= P_NONEWS && i < P_NONEWS + 256) params_f[i] = ldf(no_news, i - P_NONEWS, bf);
    }
}

// ---------------- single-pass online-softmax attention pool ----------------
// 1 block/row, 4 waves. Wave w owns articles a = w, w+4, ... Each article is
// read from HBM exactly once; score + rescaled accumulation in registers.
#define ONLINE_STEP                                                          \
    {                                                                        \
        float s = 0.f;                                                       \
        _Pragma("unroll")                                                    \
        for (int k = 0; k < 12; ++k) s = fmaf(art[k], wfrag[k], s);          \
        _Pragma("unroll")                                                    \
        for (int off = 32; off; off >>= 1) s += __shfl_xor(s, off);          \
        s += bias;                                                           \
        float mn = fmaxf(m, s);                                              \
        float scale = __expf(m - mn);                                        \
        float p = __expf(s - mn);                                            \
        l = l * scale + p;                                                   \
        _Pragma("unroll")                                                    \
        for (int k = 0; k < 12; ++k) acc[k] = fmaf(p, art[k], acc[k] * scale); \
        m = mn;                                                              \
    }

__global__ __launch_bounds__(256) void pool_kernel(const void* __restrict__ articles,
                                                   const int* __restrict__ counts32,
                                                   const int* __restrict__ flags,
                                                   const float* __restrict__ params_f,
                                                   float* __restrict__ pooled) {
    __shared__ float lds_acc[4][D_DIM];   // 12 KB
    __shared__ float lds_m[4];
    __shared__ float lds_l[4];

    const int n = blockIdx.x, t = threadIdx.x;
    const int wave = t >> 6, lane = t & 63;
    const int c = counts32[flags[1] ? 2 * n : n];

    if (c <= 0) {
        #pragma unroll
        for (int j = 0; j < 3; ++j) pooled[(size_t)n * D_DIM + t + 256 * j] = 0.0f;
        return;
    }

    // per-lane attn_w fragment: d = 4*(lane+64j)+k
    float wfrag[12];
    #pragma unroll
    for (int j = 0; j < 3; ++j) {
        float4 wv = *(const float4*)(params_f + 4 * (lane + 64 * j));
        wfrag[4 * j + 0] = wv.x; wfrag[4 * j + 1] = wv.y;
        wfrag[4 * j + 2] = wv.z; wfrag[4 * j + 3] = wv.w;
    }
    const float bias = params_f[P_ATTNB];

    float m = -1e30f, l = 0.f;
    float acc[12];
    #pragma unroll
    for (int k = 0; k < 12; ++k) acc[k] = 0.f;

    if (flags[0]) {   // bf16 articles
        const u16* base = (const u16*)articles + (size_t)n * A_ART * D_DIM;
        for (int a = wave; a < c; a += 4) {
            float art[12];
            #pragma unroll
            for (int j = 0; j < 3; ++j) {
                uint2 q = *(const uint2*)(base + a * D_DIM + 4 * (lane + 64 * j));
                art[4 * j + 0] = bf2f((u16)(q.x & 0xffffu));
                art[4 * j + 1] = bf2f((u16)(q.x >> 16));
                art[4 * j + 2] = bf2f((u16)(q.y & 0xffffu));
                art[4 * j + 3] = bf2f((u16)(q.y >> 16));
            }
            ONLINE_STEP
        }
    } else {          // f32 articles
        const float* base = (const float*)articles + (size_t)n * A_ART * D_DIM;
        for (int a = wave; a < c; a += 4) {
            float art[12];
            #pragma unroll
            for (int j = 0; j < 3; ++j) {
                float4 q = *(const float4*)(base + a * D_DIM + 4 * (lane + 64 * j));
                art[4 * j + 0] = q.x; art[4 * j + 1] = q.y;
                art[4 * j + 2] = q.z; art[4 * j + 3] = q.w;
            }
            ONLINE_STEP
        }
    }

    // merge 4 waves via LDS (single sync)
    if (lane == 0) { lds_m[wave] = m; lds_l[wave] = l; }
    #pragma unroll
    for (int j = 0; j < 3; ++j) {
        *((float4*)&lds_acc[wave][4 * (lane + 64 * j)]) =
            make_float4(acc[4 * j + 0], acc[4 * j + 1], acc[4 * j + 2], acc[4 * j + 3]);
    }
    __syncthreads();

    float M = fmaxf(fmaxf(lds_m[0], lds_m[1]), fmaxf(lds_m[2], lds_m[3]));
    float e0 = __expf(lds_m[0] - M), e1 = __expf(lds_m[1] - M);
    float e2 = __expf(lds_m[2] - M), e3 = __expf(lds_m[3] - M);
    float L = lds_l[0] * e0 + lds_l[1] * e1 + lds_l[2] * e2 + lds_l[3] * e3;
    float invL = __frcp_rn(L);

    #pragma unroll
    for (int j = 0; j < 3; ++j) {
        const int d = t + 256 * j;
        float v = lds_acc[0][d] * e0 + lds_acc[1][d] * e1
                + lds_acc[2][d] * e2 + lds_acc[3][d] * e3;
        pooled[(size_t)n * D_DIM + d] = v * invL;
    }
}

// ---------------- projection + LN + GELU + no_news select ----------------
__global__ __launch_bounds__(256) void proj_kernel(const float* __restrict__ pooled,
                                                   const float* __restrict__ projw_f,
                                                   const float* __restrict__ params_f,
                                                   const int* __restrict__ counts32,
                                                   const int* __restrict__ flags,
                                                   void* __restrict__ out) {
    __shared__ float lds_p[R_TILE * P_STR];
    __shared__ float lds_s[R_TILE * 16];
    __shared__ float lds_q[R_TILE * 16];
    __shared__ float lds_mu[R_TILE];
    __shared__ float lds_rs[R_TILE];

    const int t = threadIdx.x;
    const int row0 = blockIdx.x * R_TILE;
    const bool out_bf = flags[0] != 0;
    const bool c64 = flags[1] != 0;

    const float4* src = (const float4*)(pooled + (size_t)row0 * D_DIM);
    for (int q = t; q < R_TILE * (D_DIM / 4); q += 256) {
        int r  = q / (D_DIM / 4);
        int dc = (q % (D_DIM / 4)) * 4;
        *((float4*)&lds_p[r * P_STR + dc]) = src[q];
    }
    __syncthreads();

    const int r  = t & 15;
    const int ob = (t >> 4) * 16;

    float acc[16];
    #pragma unroll
    for (int j = 0; j < 16; ++j) acc[j] = 0.f;

    for (int d = 0; d < D_DIM; ++d) {
        const float pv = lds_p[r * P_STR + d];
        const float4* wrow = (const float4*)(projw_f + d * O_DIM + ob);
        float4 wa = wrow[0], wb = wrow[1], wc = wrow[2], wd = wrow[3];
        acc[0]  = fmaf(pv, wa.x, acc[0]);  acc[1]  = fmaf(pv, wa.y, acc[1]);
        acc[2]  = fmaf(pv, wa.z, acc[2]);  acc[3]  = fmaf(pv, wa.w, acc[3]);
        acc[4]  = fmaf(pv, wb.x, acc[4]);  acc[5]  = fmaf(pv, wb.y, acc[5]);
        acc[6]  = fmaf(pv, wb.z, acc[6]);  acc[7]  = fmaf(pv, wb.w, acc[7]);
        acc[8]  = fmaf(pv, wc.x, acc[8]);  acc[9]  = fmaf(pv, wc.y, acc[9]);
        acc[10] = fmaf(pv, wc.z, acc[10]); acc[11] = fmaf(pv, wc.w, acc[11]);
        acc[12] = fmaf(pv, wd.x, acc[12]); acc[13] = fmaf(pv, wd.y, acc[13]);
        acc[14] = fmaf(pv, wd.z, acc[14]); acc[15] = fmaf(pv, wd.w, acc[15]);
    }

    float ps = 0.f, pq = 0.f;
    #pragma unroll
    for (int j = 0; j < 16; ++j) {
        acc[j] += params_f[P_PROJB + ob + j];
        ps += acc[j];
        pq += acc[j] * acc[j];
    }
    lds_s[r * 16 + (t >> 4)] = ps;
    lds_q[r * 16 + (t >> 4)] = pq;
    __syncthreads();

    if (t < 16) {
        float s = 0.f, q = 0.f;
        #pragma unroll
        for (int g = 0; g < 16; ++g) { s += lds_s[t * 16 + g]; q += lds_q[t * 16 + g]; }
        float mu  = s * (1.0f / O_DIM);
        float var = q * (1.0f / O_DIM) - mu * mu;
        lds_mu[t] = mu;
        lds_rs[t] = rsqrtf(var + LN_EPS);
    }
    __syncthreads();

    const float mu = lds_mu[r];
    const float rs = lds_rs[r];
    const int row = row0 + r;
    const int cnt = counts32[c64 ? 2 * row : row];

    float vals[16];
    #pragma unroll
    for (int j = 0; j < 16; ++j) {
        const int o = ob + j;
        float x = (acc[j] - mu) * rs * params_f[P_LNW + o] + params_f[P_LNB + o];
        float g = 0.5f * x * (1.0f + erff(x * 0.70710678118654752f));
        vals[j] = (cnt > 0) ? g : params_f[P_NONEWS + o];
    }

    if (out_bf) {
        u16 obuf[16];
        #pragma unroll
        for (int j = 0; j < 16; ++j) obuf[j] = f2bf(vals[j]);
        uint4* dst = (uint4*)((u16*)out + (size_t)row * O_DIM + ob);
        dst[0] = *((const uint4*)&obuf[0]);
        dst[1] = *((const uint4*)&obuf[8]);
    } else {
        float4* dst = (float4*)((float*)out + (size_t)row * O_DIM + ob);
        dst[0] = *((const float4*)&vals[0]);
        dst[1] = *((const float4*)&vals[4]);
        dst[2] = *((const float4*)&vals[8]);
        dst[3] = *((const float4*)&vals[12]);
    }
}

extern "C" void kernel_launch(void* const* d_in, const int* in_sizes, int n_in,
                              void* d_out, int out_size, void* d_ws, size_t ws_size,
                              hipStream_t stream) {
    const void* articles = d_in[0];
    const int*  counts   = (const int*)d_in[1];

    int*   flags    = (int*)d_ws;
    float* projw_f  = (float*)((char*)d_ws + WS_PROJW);
    float* params_f = (float*)((char*)d_ws + WS_PARAMS);
    float* pooled   = (float*)((char*)d_ws + WS_POOLED);

    detect_kernel<<<1, 64, 0, stream>>>((const u32*)articles, counts, flags);
    params_kernel<<<776, 256, 0, stream>>>(d_in[2], d_in[3], d_in[5], d_in[6], d_in[7],
                                           d_in[8], d_in[4], flags, projw_f, params_f);
    pool_kernel<<<N_ROWS, 256, 0, stream>>>(articles, counts, flags, params_f, pooled);
    proj_kernel<<<N_ROWS / R_TILE, 256, 0, stream>>>(pooled, projw_f, params_f, counts,
                                                     flags, d_out);
}